// Round 1
// baseline (2340.962 us; speedup 1.0000x reference)
//
#include <hip/hip_runtime.h>
#include <cstdint>
#include <cstddef>

// Problem constants
#define MB_   8192            // batch
#define NPX   2048            // masked features
#define NAX   256             // addon
#define NCX   32              // covariates
#define NOX   20000           // output features
#define KTOT  2336            // 2048+256+32
#define KP    2368            // K padded to multiple of 64 (37 tiles)
#define NPAD  20096           // N padded to multiple of 128 (157 tiles)

typedef __bf16 bf16;
typedef bf16  bf16x8 __attribute__((ext_vector_type(8)));
typedef float f32x4  __attribute__((ext_vector_type(4)));

__device__ __forceinline__ uint16_t f2bf(float f) {
  union { float f; uint32_t u; } v; v.f = f;
  uint32_t u = v.u;
  return (uint16_t)((u + 0x7FFFu + ((u >> 16) & 1u)) >> 16);  // RNE
}

__device__ __forceinline__ void gl_lds16(const void* g, void* l) {
  __builtin_amdgcn_global_load_lds(
      (const __attribute__((address_space(1))) void*)g,
      (__attribute__((address_space(3))) void*)l,
      16, 0, 0);
}

// ---------------------------------------------------------------------------
// Pre-pass 1: zc[m][k] = bf16( k<2304 ? z[m][k] : (k<2336 ? cat[m][k-2304] : 0) )
// One thread -> 8 consecutive k (one 16B store). 2368/8 = 296 chunks/row.
// Region boundaries (2304, 2336) are multiples of 8 -> no mixed chunks.
// ---------------------------------------------------------------------------
__global__ __launch_bounds__(256) void build_zc(
    const float* __restrict__ z, const float* __restrict__ cat,
    uint4* __restrict__ zc)
{
  int t = blockIdx.x * 256 + threadIdx.x;     // exactly 8192*296 threads
  int m = t / 296, kb = t % 296;
  union { uint16_t u[8]; uint4 v; } U;
  if (kb < 288) {
    const float* p = z + (size_t)m * (NPX + NAX) + kb * 8;
    #pragma unroll
    for (int j = 0; j < 8; ++j) U.u[j] = f2bf(p[j]);
  } else if (kb < 292) {
    const float* p = cat + (size_t)m * NCX + (kb - 288) * 8;
    #pragma unroll
    for (int j = 0; j < 8; ++j) U.u[j] = f2bf(p[j]);
  } else {
    #pragma unroll
    for (int j = 0; j < 8; ++j) U.u[j] = 0;
  }
  zc[t] = U.v;
}

// ---------------------------------------------------------------------------
// Pre-pass 2: WcT[n][k] = bf16 of combined weight, transposed via LDS tiles.
// 64(k) x 64(n) tiles; reads coalesced along n, writes coalesced along k.
// ---------------------------------------------------------------------------
__device__ __forceinline__ float wval(int k, int n,
    const float* __restrict__ Wm, const float* __restrict__ Mk,
    const float* __restrict__ Wa, const float* __restrict__ Am,
    const float* __restrict__ Wc)
{
  if (k < NPX)        return Wm[(size_t)k * NOX + n] * Mk[(size_t)k * NOX + n];
  if (k < NPX + NAX)  { int kk = k - NPX;       return Wa[(size_t)kk * NOX + n] * Am[(size_t)kk * NOX + n]; }
  if (k < KTOT)       { int kk = k - NPX - NAX; return Wc[(size_t)kk * NOX + n]; }
  return 0.f;
}

__global__ __launch_bounds__(256) void build_wct(
    const float* __restrict__ Wm, const float* __restrict__ Mk,
    const float* __restrict__ Wa, const float* __restrict__ Am,
    const float* __restrict__ Wc, uint16_t* __restrict__ wct)
{
  __shared__ float tile[64][65];
  const int n0 = blockIdx.x * 64;   // 314 tiles (NPAD/64)
  const int k0 = blockIdx.y * 64;   // 37 tiles  (KP/64)
  const int t = threadIdx.x;
  {
    const int nl = t & 63, kl0 = t >> 6;
    #pragma unroll
    for (int p = 0; p < 16; ++p) {
      int kl = p * 4 + kl0;
      int k = k0 + kl, n = n0 + nl;
      float v = 0.f;
      if (n < NOX) v = wval(k, n, Wm, Mk, Wa, Am, Wc);
      tile[kl][nl] = v;
    }
  }
  __syncthreads();
  {
    const int kl = t & 63, nl0 = t >> 6;
    #pragma unroll
    for (int p = 0; p < 16; ++p) {
      int nl = p * 4 + nl0;
      int n = n0 + nl;                       // n < 20096 always
      wct[(size_t)n * KP + k0 + kl] = f2bf(tile[kl][nl]);
    }
  }
}

// ---------------------------------------------------------------------------
// GEMM: C[M][NOX] (f32 logits) = A[M][KP](bf16) @ WcT[N][KP](bf16)^T
// 128x128 block tile, 4 waves -> 64x64 per wave, BK=64, 16x16x32 MFMA.
// global_load_lds width-16 staging (m97 structure).
// ---------------------------------------------------------------------------
__global__ __launch_bounds__(256) void gemm_bt(
    const uint16_t* __restrict__ Ag, const uint16_t* __restrict__ Bg,
    float* __restrict__ C)
{
  __shared__ bf16 sA[128 * 64];
  __shared__ bf16 sB[128 * 64];
  const int tid  = threadIdx.x;
  const int lane = tid & 63;
  const int w    = tid >> 6;
  const int m0 = blockIdx.y * 128;
  const int n0 = blockIdx.x * 128;
  const int wm = (w >> 1) * 64;
  const int wn = (w & 1)  * 64;
  const int r15 = lane & 15;
  const int q4  = lane >> 4;
  const int lrow = lane >> 3;       // 0..7
  const int lkof = (lane & 7) * 8;  // 0..56 (x2B = 16B chunks)

  f32x4 acc[4][4] = {};

  for (int kt = 0; kt < KP / 64; ++kt) {
    const int kb = kt * 64;
    #pragma unroll
    for (int q = 0; q < 4; ++q) {
      const int rowA = w * 32 + q * 8;   // wave-uniform
      gl_lds16(Ag + ((size_t)(m0 + rowA + lrow) * KP + kb + lkof), &sA[rowA * 64]);
      gl_lds16(Bg + ((size_t)(n0 + rowA + lrow) * KP + kb + lkof), &sB[rowA * 64]);
    }
    __syncthreads();
    #pragma unroll
    for (int ks = 0; ks < 2; ++ks) {
      const int ko = ks * 32 + q4 * 8;
      bf16x8 av[4], bv[4];
      #pragma unroll
      for (int i = 0; i < 4; ++i)
        av[i] = *(const bf16x8*)&sA[(wm + i * 16 + r15) * 64 + ko];
      #pragma unroll
      for (int j = 0; j < 4; ++j)
        bv[j] = *(const bf16x8*)&sB[(wn + j * 16 + r15) * 64 + ko];
      #pragma unroll
      for (int i = 0; i < 4; ++i)
        #pragma unroll
        for (int j = 0; j < 4; ++j)
          acc[i][j] = __builtin_amdgcn_mfma_f32_16x16x32_bf16(av[i], bv[j], acc[i][j], 0, 0, 0);
    }
    __syncthreads();
  }

  #pragma unroll
  for (int i = 0; i < 4; ++i) {
    const int row = m0 + wm + i * 16 + q4 * 4;
    #pragma unroll
    for (int j = 0; j < 4; ++j) {
      const int col = n0 + wn + j * 16 + r15;
      if (col < NOX) {
        #pragma unroll
        for (int rr = 0; rr < 4; ++rr)
          C[(size_t)(row + rr) * NOX + col] = acc[i][j][rr];
      }
    }
  }
}

// ---------------------------------------------------------------------------
// Softmax + library-size scale, in place on logits. One block per row.
// ---------------------------------------------------------------------------
__global__ __launch_bounds__(256) void softmax_scale(
    float* __restrict__ io, const float* __restrict__ lls)
{
  const int m = blockIdx.x;
  float* row = io + (size_t)m * NOX;
  float4* row4 = (float4*)row;
  const int t = threadIdx.x;

  float mx = -1e30f, sm = 0.f;
  for (int i = t; i < NOX / 4; i += 256) {
    float4 v = row4[i];
    float lm = fmaxf(fmaxf(v.x, v.y), fmaxf(v.z, v.w));
    if (lm > mx) { sm *= __expf(mx - lm); mx = lm; }
    sm += __expf(v.x - mx) + __expf(v.y - mx) + __expf(v.z - mx) + __expf(v.w - mx);
  }
  // wave-64 reduce
  #pragma unroll
  for (int off = 32; off > 0; off >>= 1) {
    float mo = __shfl_down(mx, off);
    float so = __shfl_down(sm, off);
    float nm = fmaxf(mx, mo);
    sm = sm * __expf(mx - nm) + so * __expf(mo - nm);
    mx = nm;
  }
  __shared__ float red_m[4], red_s[4], fin[2];
  const int lane = t & 63, wv = t >> 6;
  if (lane == 0) { red_m[wv] = mx; red_s[wv] = sm; }
  __syncthreads();
  if (t == 0) {
    float M = red_m[0], S = red_s[0];
    #pragma unroll
    for (int i = 1; i < 4; ++i) {
      float nm = fmaxf(M, red_m[i]);
      S = S * __expf(M - nm) + red_s[i] * __expf(red_m[i] - nm);
      M = nm;
    }
    fin[0] = M;
    fin[1] = __expf(lls[m]) / S;
  }
  __syncthreads();
  const float M = fin[0], Cf = fin[1];
  for (int i = t; i < NOX / 4; i += 256) {
    float4 v = row4[i];
    v.x = __expf(v.x - M) * Cf;
    v.y = __expf(v.y - M) * Cf;
    v.z = __expf(v.z - M) * Cf;
    v.w = __expf(v.w - M) * Cf;
    row4[i] = v;
  }
}

// ---------------------------------------------------------------------------
extern "C" void kernel_launch(void* const* d_in, const int* in_sizes, int n_in,
                              void* d_out, int out_size, void* d_ws, size_t ws_size,
                              hipStream_t stream) {
  const float* z    = (const float*)d_in[0];  // (8192, 2304)
  const float* lls  = (const float*)d_in[1];  // (8192, 1)
  const float* cat  = (const float*)d_in[2];  // (8192, 32)
  const float* mask = (const float*)d_in[3];  // (2048, 20000)
  const float* am   = (const float*)d_in[4];  // (256, 20000)
  const float* Wm   = (const float*)d_in[5];  // (2048, 20000)
  const float* Wa   = (const float*)d_in[6];  // (256, 20000)
  const float* Wc   = (const float*)d_in[7];  // (32, 20000)
  float* out = (float*)d_out;                 // (8192, 20000)

  uint16_t* zc  = (uint16_t*)d_ws;                       // 8192*2368*2  = 38.8 MB
  uint16_t* wct = zc + (size_t)MB_ * KP;                 // 20096*2368*2 = 95.2 MB

  build_zc<<<(MB_ * (KP / 8)) / 256, 256, 0, stream>>>(z, cat, (uint4*)zc);
  build_wct<<<dim3(NPAD / 64, KP / 64), 256, 0, stream>>>(Wm, mask, Wa, am, Wc, wct);
  gemm_bt<<<dim3(NPAD / 128, MB_ / 128), 256, 0, stream>>>(zc, wct, out);
  softmax_scale<<<MB_, 256, 0, stream>>>(out, lls);
}